// Round 12
// baseline (180.023 us; speedup 1.0000x reference)
//
#include <hip/hip_runtime.h>

typedef __attribute__((ext_vector_type(8))) short bf16x8;
typedef __attribute__((ext_vector_type(4))) float f32x4;
typedef __attribute__((ext_vector_type(8))) unsigned short u16x8;

#define DEVINL __device__ __forceinline__
#define AS1 __attribute__((address_space(1)))
#define AS3 __attribute__((address_space(3)))

constexpr int NI = 256;   // input channels (K)
constexpr int NO = 256;   // output channels
constexpr int NC = 120;   // irrep feature width
constexpr int BROW = NC * NI;                        // 30720: one b-row of xt
constexpr int WELEMS = 56 * NO * NI;                 // 3,670,016
constexpr size_t XT_ELEMS = (size_t)NC * 1024 * NI;  // 31,457,280

DEVINL ushort f2bf(float x) {   // round-to-nearest-even fp32 -> bf16 bits
  unsigned u = __float_as_uint(x);
  u += 0x7FFFu + ((u >> 16) & 1u);
  return (ushort)(u >> 16);
}

constexpr int mat_of(int c) {   // column c -> weight-matrix id (0..55); monotone
  return c < 32 ? c : (c < 80 ? 32 + (c - 32) / 3 : 48 + (c - 80) / 5);
}

// ---- prep: wb[((m*32 + k/8)*256 + o)*8 + k%8] = bf16(W_m[o][k]) ----
__global__ __launch_bounds__(256) void prep_w(const float* __restrict__ w0,
                                              const float* __restrict__ w1,
                                              const float* __restrict__ w2,
                                              ushort* __restrict__ wb) {
  const int m = blockIdx.x >> 5;        // 0..55
  const int kc = blockIdx.x & 31;       // k-chunk of 8
  const int o = threadIdx.x;            // 0..255
  const float* src;
  if (m < 32)      src = w0 + ((size_t)(m * NO + o)) * NI;
  else if (m < 48) src = w1 + ((size_t)((m - 32) * NO + o)) * NI;
  else             src = w2 + ((size_t)((m - 48) * NO + o)) * NI;
  src += kc * 8;
  float4 a = *reinterpret_cast<const float4*>(src);
  float4 b = *reinterpret_cast<const float4*>(src + 4);
  u16x8 p = { f2bf(a.x), f2bf(a.y), f2bf(a.z), f2bf(a.w),
              f2bf(b.x), f2bf(b.y), f2bf(b.z), f2bf(b.w) };
  *reinterpret_cast<u16x8*>(wb + ((size_t)(blockIdx.x * 256 + o)) * 8) = p;
}

// ---- pass 1: x [1024 b][256 i][120 c] f32 -> xt [1024 b][120 c][256 i] bf16 ----
// (R11 v3, unchanged: contiguous reads/writes; LDS f32 [i][c] stride 121)
__global__ __launch_bounds__(256) void xpose(const float* __restrict__ x,
                                             ushort* __restrict__ xt) {
  __shared__ float tl[64 * 121];       // 31 KB -> 5 blocks/CU
  const int bid = blockIdx.x;          // 4096 = b*4 + iq
  const int b = bid >> 2, iq = bid & 3;
  const int t = threadIdx.x;
  const float* xb = x + (size_t)b * BROW + (size_t)iq * 64 * NC;
#pragma unroll
  for (int j = 0; j < 15; ++j) {       // 7680 f32, float2 coalesced reads
    const int e = (j * 256 + t) * 2;   // even -> c even, no row wrap (c<=118)
    float2 v = *reinterpret_cast<const float2*>(xb + e);
    const int i = e / 120, c = e % 120;
    tl[i * 121 + c] = v.x;
    tl[i * 121 + c + 1] = v.y;
  }
  __syncthreads();
  ushort* dst = xt + (size_t)b * BROW + iq * 64;
#pragma unroll
  for (int q = 0; q < 4; ++q) {        // 960 chunks (120 c x 8 ich), predicated
    const int chunk = q * 256 + t;
    if (chunk < 960) {
      const int c = chunk >> 3, ich = chunk & 7;
      u16x8 p;
#pragma unroll
      for (int k = 0; k < 8; ++k) p[k] = f2bf(tl[(ich * 8 + k) * 121 + c]);
      *reinterpret_cast<u16x8*>(dst + (size_t)c * NI + ich * 8) = p;
    }
  }
}

// ---- pass 2 (FUSED): 8c x 16b x 256o blocks, staged via global_load_lds from
// xt, W in <=8-frag bursts (template-folded matrix map), DIRECT f32 out
// (two float4 = one aligned 32B sector per (b,o) -- R5-proven store class).
template<int CT>
DEVINL void body8(const ushort* __restrict__ xt, const ushort* __restrict__ wb,
                  const float* __restrict__ bias0, float* __restrict__ out,
                  int bt, ushort* xs) {
  constexpr int c0 = CT * 8;
  constexpr int M0 = mat_of(c0);
  constexpr int NM = mat_of(c0 + 7) - M0 + 1;   // 8 (CT<4) else 2..4
  constexpr int NCH = (NM > 4) ? 2 : 1;         // cc-chunks per kh
  constexpr int CPC = 8 / NCH;                  // cc per chunk
  constexpr int MPC = (NM > 4) ? 4 : NM;        // matrices per burst (<=4)

  const int tid = threadIdx.x, lane = tid & 63, w = tid >> 6;  // 8 waves
  const int rb = lane & 15, rg = lane >> 4;
  const int bg = bt * 16;
  const int oc = w * 16 + rb;                   // o-col (+ of*128)

  // staging: lane l, instr j -> b-sub = 8j + (l>>3), c-row = c0 + w,
  // global chunk' = (l&7) ^ (l>>3); LDS dst linear (HW rule), row = 16w+8j+(l>>3)
  const ushort* g0 = xt + (size_t)(bg + (lane >> 3)) * BROW + (size_t)(c0 + w) * NI
                        + (((lane & 7) ^ (lane >> 3)) * 8);
  const ushort* g1 = g0 + (size_t)8 * BROW;

  f32x4 acc[8][2];
#pragma unroll
  for (int i = 0; i < 8; ++i) { acc[i][0] = (f32x4)0.0f; acc[i][1] = (f32x4)0.0f; }

#define STAGE8(BUF, S)                                                          \
  do {                                                                          \
    __builtin_amdgcn_global_load_lds((const AS1 void*)(g0 + (S) * 64),          \
        (AS3 void*)(xs + (BUF) * 8192 + w * 1024), 16, 0, 0);                   \
    __builtin_amdgcn_global_load_lds((const AS1 void*)(g1 + (S) * 64),          \
        (AS3 void*)(xs + (BUF) * 8192 + w * 1024 + 512), 16, 0, 0);             \
  } while (0)

  STAGE8(0, 0);
  __syncthreads();                     // drains vmcnt: stage 0 ready

#pragma unroll 1
  for (int s = 0; s < 4; ++s) {
    if (s < 3) STAGE8((s + 1) & 1, s + 1);      // prefetch next stage
    const ushort* xb = xs + (s & 1) * 8192;
#pragma unroll
    for (int kh = 0; kh < 2; ++kh) {
#pragma unroll
      for (int ch = 0; ch < NCH; ++ch) {
        bf16x8 wf[MPC][2];             // <=8 frags (32 VGPR), burst-issued
#pragma unroll
        for (int jm = 0; jm < MPC; ++jm)
#pragma unroll
          for (int of = 0; of < 2; ++of)
            wf[jm][of] = *reinterpret_cast<const bf16x8*>(
                wb + ((size_t)(((M0 + ch * MPC + jm) * 32 + s * 8 + kh * 4 + rg) * NO
                               + oc + of * 128)) * 8);
#pragma unroll
        for (int cl = 0; cl < CPC; ++cl) {
          const int cc = ch * CPC + cl;
          const int jm = mat_of(c0 + cc) - M0 - ch * MPC;   // compile-time
          bf16x8 a = *reinterpret_cast<const bf16x8*>(
              xb + (cc * 16 + rb) * 64 + (((kh * 4 + rg) ^ (rb & 7)) * 8));
          acc[cc][0] = __builtin_amdgcn_mfma_f32_16x16x32_bf16(a, wf[jm][0],
                                                               acc[cc][0], 0, 0, 0);
          acc[cc][1] = __builtin_amdgcn_mfma_f32_16x16x32_bf16(a, wf[jm][1],
                                                               acc[cc][1], 0, 0, 0);
        }
      }
    }
    __syncthreads();                   // drains prefetch; protects buf reuse
  }
#undef STAGE8

  if constexpr (CT < 4) {              // l=0 irreps: bias b0[c][o]
#pragma unroll
    for (int cc = 0; cc < 8; ++cc) {
      acc[cc][0] += bias0[(c0 + cc) * NO + oc];
      acc[cc][1] += bias0[(c0 + cc) * NO + oc + 128];
    }
  }

  const int br0 = bg + rg * 4;         // D row = (lane>>4)*4 + reg
#pragma unroll
  for (int of = 0; of < 2; ++of)
#pragma unroll
    for (int r = 0; r < 4; ++r) {
      float4 va = make_float4(acc[0][of][r], acc[1][of][r], acc[2][of][r], acc[3][of][r]);
      float4 vb = make_float4(acc[4][of][r], acc[5][of][r], acc[6][of][r], acc[7][of][r]);
      float* dst = out + ((size_t)(br0 + r) * NO + oc + of * 128) * NC + c0;
      *reinterpret_cast<float4*>(dst) = va;       // 32B sector, aligned
      *reinterpret_cast<float4*>(dst + 4) = vb;
    }
}

__global__ __launch_bounds__(512, 4) void e3mix8(const ushort* __restrict__ xt,
                                                 const ushort* __restrict__ wb,
                                                 const float* __restrict__ bias0,
                                                 float* __restrict__ out) {
  __shared__ ushort xs[2 * 8192];      // 32 KB double-buffer
  const int bid = blockIdx.x;          // 960 = 64 bt x 15 ct, ct FASTEST (balance)
  const int ct = bid % 15;
  const int bt = bid / 15;
  switch (ct) {
    case 0:  body8<0 >(xt, wb, bias0, out, bt, xs); break;
    case 1:  body8<1 >(xt, wb, bias0, out, bt, xs); break;
    case 2:  body8<2 >(xt, wb, bias0, out, bt, xs); break;
    case 3:  body8<3 >(xt, wb, bias0, out, bt, xs); break;
    case 4:  body8<4 >(xt, wb, bias0, out, bt, xs); break;
    case 5:  body8<5 >(xt, wb, bias0, out, bt, xs); break;
    case 6:  body8<6 >(xt, wb, bias0, out, bt, xs); break;
    case 7:  body8<7 >(xt, wb, bias0, out, bt, xs); break;
    case 8:  body8<8 >(xt, wb, bias0, out, bt, xs); break;
    case 9:  body8<9 >(xt, wb, bias0, out, bt, xs); break;
    case 10: body8<10>(xt, wb, bias0, out, bt, xs); break;
    case 11: body8<11>(xt, wb, bias0, out, bt, xs); break;
    case 12: body8<12>(xt, wb, bias0, out, bt, xs); break;
    case 13: body8<13>(xt, wb, bias0, out, bt, xs); break;
    default: body8<14>(xt, wb, bias0, out, bt, xs); break;
  }
}

// ---- fallback (small ws): direct strided gather from x, validated in R5 ----
__global__ __launch_bounds__(512, 4) void e3mix2f(const float* __restrict__ x,
                                                  const ushort* __restrict__ wb,
                                                  const float* __restrict__ bias0,
                                                  float* __restrict__ out) {
  __shared__ ushort xs[8 * 16 * 64];
  const int bid = blockIdx.x;          // 960 = 15 ct * 64 bt
  const int ct = bid % 15, bt = bid / 15;
  const int c0 = ct * 8, bg = bt * 16;
  const int t = threadIdx.x, lane = t & 63, wid = t >> 6;
  const int sb = lane >> 2, sp = lane & 3;
  const int rb = lane & 15, rg = lane >> 4;
  const int oc = wid * 16 + rb;
  const int srow = (wid * 16 + sb) * 64;
  const int sk0 = (sp * 16) ^ ((sb & 7) << 3);
  const int sk1 = (sp * 16 + 8) ^ ((sb & 7) << 3);

  f32x4 acc[8][2];
#pragma unroll
  for (int i = 0; i < 8; ++i) { acc[i][0] = (f32x4)0.0f; acc[i][1] = (f32x4)0.0f; }
  bf16x8 w00 = {}, w01 = {}, w10 = {}, w11 = {};

#pragma unroll 1
  for (int s = 0; s < 4; ++s) {
    if (s) __syncthreads();
    u16x8 v0, v1;
    const float* src = x + (size_t)(bg + sb) * (NI * NC)
                         + (size_t)(s * 64 + sp * 16) * NC + (c0 + wid);
#pragma unroll
    for (int jj = 0; jj < 8; ++jj) v0[jj] = f2bf(src[jj * NC]);
#pragma unroll
    for (int jj = 0; jj < 8; ++jj) v1[jj] = f2bf(src[(8 + jj) * NC]);
    *reinterpret_cast<u16x8*>(&xs[srow + sk0]) = v0;
    *reinterpret_cast<u16x8*>(&xs[srow + sk1]) = v1;
    __syncthreads();

    int mprev = -1;
#pragma unroll
    for (int cc = 0; cc < 8; ++cc) {
      const int c = c0 + cc;
      const int m = c < 32 ? c : (c < 80 ? 32 + (c - 32) / 3 : 48 + (c - 80) / 5);
      if (m != mprev) {
        const ushort* wp = wb + ((size_t)((m * 32 + s * 8 + rg) * NO + oc)) * 8;
        w00 = *reinterpret_cast<const bf16x8*>(wp);
        w10 = *reinterpret_cast<const bf16x8*>(wp + (size_t)4 * NO * 8);
        w01 = *reinterpret_cast<const bf16x8*>(wp + 128 * 8);
        w11 = *reinterpret_cast<const bf16x8*>(wp + (size_t)4 * NO * 8 + 128 * 8);
        mprev = m;
      }
      const ushort* xp = xs + (cc * 16 + rb) * 64;
      const int sz = (rb & 7) << 3;
      bf16x8 a0 = *reinterpret_cast<const bf16x8*>(xp + ((rg * 8) ^ sz));
      bf16x8 a1 = *reinterpret_cast<const bf16x8*>(xp + ((32 + rg * 8) ^ sz));
      acc[cc][0] = __builtin_amdgcn_mfma_f32_16x16x32_bf16(a0, w00, acc[cc][0], 0, 0, 0);
      acc[cc][0] = __builtin_amdgcn_mfma_f32_16x16x32_bf16(a1, w10, acc[cc][0], 0, 0, 0);
      acc[cc][1] = __builtin_amdgcn_mfma_f32_16x16x32_bf16(a0, w01, acc[cc][1], 0, 0, 0);
      acc[cc][1] = __builtin_amdgcn_mfma_f32_16x16x32_bf16(a1, w11, acc[cc][1], 0, 0, 0);
    }
  }

  if (c0 < 32) {
#pragma unroll
    for (int cc = 0; cc < 8; ++cc) {
      acc[cc][0] += bias0[(c0 + cc) * NO + oc];
      acc[cc][1] += bias0[(c0 + cc) * NO + oc + 128];
    }
  }

  const int br0 = bg + rg * 4;
#pragma unroll
  for (int of = 0; of < 2; ++of)
#pragma unroll
    for (int r = 0; r < 4; ++r) {
      float4 va = make_float4(acc[0][of][r], acc[1][of][r], acc[2][of][r], acc[3][of][r]);
      float4 vb = make_float4(acc[4][of][r], acc[5][of][r], acc[6][of][r], acc[7][of][r]);
      float* dst = out + ((size_t)(br0 + r) * NO + oc + of * 128) * NC + c0;
      *reinterpret_cast<float4*>(dst) = va;
      *reinterpret_cast<float4*>(dst + 4) = vb;
    }
}

extern "C" void kernel_launch(void* const* d_in, const int* in_sizes, int n_in,
                              void* d_out, int out_size, void* d_ws, size_t ws_size,
                              hipStream_t stream) {
  const float* x  = (const float*)d_in[0];
  const float* w0 = (const float*)d_in[1];
  const float* w1 = (const float*)d_in[2];
  const float* w2 = (const float*)d_in[3];
  const float* b0 = (const float*)d_in[4];
  float* out = (float*)d_out;
  ushort* wb = (ushort*)d_ws;                       // 7.34 MB
  ushort* xt = wb + WELEMS;                         // +62.9 MB

  prep_w<<<56 * 32, 256, 0, stream>>>(w0, w1, w2, wb);
  const bool big = ws_size >= (size_t)2 * (WELEMS + XT_ELEMS);
  if (big) {
    xpose<<<4096, 256, 0, stream>>>(x, xt);
    e3mix8<<<960, 512, 0, stream>>>(xt, wb, b0, out);
  } else {
    e3mix2f<<<960, 512, 0, stream>>>(x, wb, b0, out);
  }
}

// Round 13
// 161.869 us; speedup vs baseline: 1.1121x; 1.1121x over previous
//
#include <hip/hip_runtime.h>

typedef __attribute__((ext_vector_type(8))) short bf16x8;
typedef __attribute__((ext_vector_type(4))) float f32x4;
typedef __attribute__((ext_vector_type(8))) unsigned short u16x8;

#define DEVINL __device__ __forceinline__
#define AS1 __attribute__((address_space(1)))
#define AS3 __attribute__((address_space(3)))

constexpr int NI = 256;   // input channels (K)
constexpr int NO = 256;   // output channels
constexpr int NC = 120;   // irrep feature width
constexpr int BROW = NC * NI;                        // 30720: one b-row of xt
constexpr int WELEMS = 56 * NO * NI;                 // 3,670,016
constexpr size_t XT_ELEMS = (size_t)NC * 1024 * NI;  // 31,457,280

DEVINL ushort f2bf(float x) {   // round-to-nearest-even fp32 -> bf16 bits
  unsigned u = __float_as_uint(x);
  u += 0x7FFFu + ((u >> 16) & 1u);
  return (ushort)(u >> 16);
}
DEVINL float bf2f(ushort v) { return __uint_as_float((unsigned)v << 16); }

// ---- prep: wb[((m*32 + k/8)*256 + o)*8 + k%8] = bf16(W_m[o][k]) ----
__global__ __launch_bounds__(256) void prep_w(const float* __restrict__ w0,
                                              const float* __restrict__ w1,
                                              const float* __restrict__ w2,
                                              ushort* __restrict__ wb) {
  const int m = blockIdx.x >> 5;        // 0..55
  const int kc = blockIdx.x & 31;       // k-chunk of 8
  const int o = threadIdx.x;            // 0..255
  const float* src;
  if (m < 32)      src = w0 + ((size_t)(m * NO + o)) * NI;
  else if (m < 48) src = w1 + ((size_t)((m - 32) * NO + o)) * NI;
  else             src = w2 + ((size_t)((m - 48) * NO + o)) * NI;
  src += kc * 8;
  float4 a = *reinterpret_cast<const float4*>(src);
  float4 b = *reinterpret_cast<const float4*>(src + 4);
  u16x8 p = { f2bf(a.x), f2bf(a.y), f2bf(a.z), f2bf(a.w),
              f2bf(b.x), f2bf(b.y), f2bf(b.z), f2bf(b.w) };
  *reinterpret_cast<u16x8*>(wb + ((size_t)(blockIdx.x * 256 + o)) * 8) = p;
}

// ---- pass 1: x [1024 b][256 i][120 c] f32 -> xt [1024 b][120 c][256 i] bf16 ----
// (R11 v3, unchanged: contiguous reads/writes; LDS f32 [i][c] stride 121)
__global__ __launch_bounds__(256) void xpose(const float* __restrict__ x,
                                             ushort* __restrict__ xt) {
  __shared__ float tl[64 * 121];       // 31 KB -> 5 blocks/CU
  const int bid = blockIdx.x;          // 4096 = b*4 + iq
  const int b = bid >> 2, iq = bid & 3;
  const int t = threadIdx.x;
  const float* xb = x + (size_t)b * BROW + (size_t)iq * 64 * NC;
#pragma unroll
  for (int j = 0; j < 15; ++j) {       // 7680 f32, float2 coalesced reads
    const int e = (j * 256 + t) * 2;   // even -> c even, no row wrap (c<=118)
    float2 v = *reinterpret_cast<const float2*>(xb + e);
    const int i = e / 120, c = e % 120;
    tl[i * 121 + c] = v.x;
    tl[i * 121 + c + 1] = v.y;
  }
  __syncthreads();
  ushort* dst = xt + (size_t)b * BROW + iq * 64;
#pragma unroll
  for (int q = 0; q < 4; ++q) {        // 960 chunks (120 c x 8 ich), predicated
    const int chunk = q * 256 + t;
    if (chunk < 960) {
      const int c = chunk >> 3, ich = chunk & 7;
      u16x8 p;
#pragma unroll
      for (int k = 0; k < 8; ++k) p[k] = f2bf(tl[(ich * 8 + k) * 121 + c]);
      *reinterpret_cast<u16x8*>(dst + (size_t)c * NI + ich * 8) = p;
    }
  }
}

// ---- pass 2 (FUSED, single-matrix-per-WAVE): block = 8c x 32b x 64o, 8 waves.
// Wave w owns c = c0+w -> ONE weight matrix per wave (0.5 load:MFMA ratio, W
// L2-resident). K=256 in 4 stages of 64 via global_load_lds dbuf. Epilogue:
// bf16 LDS repack [b][o][c] -> 32B-contiguous f32 out stores (no otrans pass).
__global__ __launch_bounds__(512, 4) void e3mix9(const ushort* __restrict__ xt,
                                                 const ushort* __restrict__ wb,
                                                 const float* __restrict__ bias0,
                                                 float* __restrict__ out) {
  __shared__ ushort xs[2 * 16384];     // 64 KB staging dbuf; reused by epilogue
  const int bid = blockIdx.x;          // 1920 = (bt*15 + ct)*4 + oq, oq fastest
  const int oq = bid & 3;              //  -> 4 oq-blocks share xt slice (L3 hit)
  const int rest = bid >> 2;
  const int ct = rest % 15;
  const int bt = rest / 15;
  const int c0 = ct * 8, bg = bt * 32, og = oq * 64;

  const int tid = threadIdx.x, lane = tid & 63, w = tid >> 6;   // 8 waves
  const int rb = lane & 15, rg = lane >> 4;
  const int c = c0 + w;                // wave's column
  const int m = c < 32 ? c : (c < 80 ? 32 + (c - 32) / 3 : 48 + (c - 80) / 5);

  // staging: wave w fills its own c-plane [32 b][64 k] (4 KB) with 4 instrs.
  // lane l, instr j -> b-sub = j*8 + (l>>3), chunk' = (l&7) ^ (l>>3)
  // (LDS dst linear; read side applies same XOR involution -- proven pattern)
  const int lr = lane >> 3;
  const ushort* gsrc = xt + (size_t)(bg + lr) * BROW + (size_t)c * NI
                          + ((lane & 7) ^ lr) * 8;

  f32x4 acc[2][4];                     // [fb][fo]: 32b x 64o per wave
#pragma unroll
  for (int i = 0; i < 2; ++i)
#pragma unroll
    for (int j = 0; j < 4; ++j) acc[i][j] = (f32x4)0.0f;

#define STAGE9(BUF, S)                                                         \
  do {                                                                         \
    __builtin_amdgcn_global_load_lds(                                          \
        (const AS1 void*)(gsrc + (size_t)(S) * 64 + (size_t)0 * 8 * BROW),     \
        (AS3 void*)(xs + (BUF) * 16384 + w * 2048 + 0 * 512), 16, 0, 0);       \
    __builtin_amdgcn_global_load_lds(                                          \
        (const AS1 void*)(gsrc + (size_t)(S) * 64 + (size_t)1 * 8 * BROW),     \
        (AS3 void*)(xs + (BUF) * 16384 + w * 2048 + 1 * 512), 16, 0, 0);       \
    __builtin_amdgcn_global_load_lds(                                          \
        (const AS1 void*)(gsrc + (size_t)(S) * 64 + (size_t)2 * 8 * BROW),     \
        (AS3 void*)(xs + (BUF) * 16384 + w * 2048 + 2 * 512), 16, 0, 0);       \
    __builtin_amdgcn_global_load_lds(                                          \
        (const AS1 void*)(gsrc + (size_t)(S) * 64 + (size_t)3 * 8 * BROW),     \
        (AS3 void*)(xs + (BUF) * 16384 + w * 2048 + 3 * 512), 16, 0, 0);       \
  } while (0)

  STAGE9(0, 0);
  __syncthreads();                     // stage 0 ready

#pragma unroll 1
  for (int s = 0; s < 4; ++s) {
    if (s < 3) STAGE9((s + 1) & 1, s + 1);      // prefetch next stage
    const ushort* xb = xs + (s & 1) * 16384 + w * 2048;   // wave's plane
#pragma unroll
    for (int kh = 0; kh < 2; ++kh) {   // two k-halves of 32
      bf16x8 a[2], wf[4];
#pragma unroll
      for (int fb = 0; fb < 2; ++fb)   // A frags: conflict-free swizzled reads
        a[fb] = *reinterpret_cast<const bf16x8*>(
            xb + (fb * 16 + rb) * 64 + (((kh * 4 + rg) ^ (rb & 7)) * 8));
#pragma unroll
      for (int fo = 0; fo < 4; ++fo)   // W frags: 4 x 256B coalesced, L2-hot
        wf[fo] = *reinterpret_cast<const bf16x8*>(
            wb + ((size_t)((m * 32 + s * 8 + kh * 4 + rg) * NO
                           + og + fo * 16 + rb)) * 8);
#pragma unroll
      for (int fb = 0; fb < 2; ++fb)
#pragma unroll
        for (int fo = 0; fo < 4; ++fo)
          acc[fb][fo] = __builtin_amdgcn_mfma_f32_16x16x32_bf16(a[fb], wf[fo],
                                                                acc[fb][fo], 0, 0, 0);
    }
    __syncthreads();                   // drains prefetch; protects buf reuse
  }
#undef STAGE9

  if (c0 < 32) {                       // l=0 irreps (whole block): bias b0[c][o]
#pragma unroll
    for (int fo = 0; fo < 4; ++fo) {
      const float bv = bias0[c * NO + og + fo * 16 + rb];
#pragma unroll
      for (int fb = 0; fb < 2; ++fb) acc[fb][fo] += bv;
    }
  }

  // epilogue repack: tl[b'][o][c] bf16, b'-row stride 520 u16 (pad vs banks).
  // All staging reads drained by the final barrier above; xs reused.
#pragma unroll
  for (int fb = 0; fb < 2; ++fb)
#pragma unroll
    for (int r = 0; r < 4; ++r)
#pragma unroll
      for (int fo = 0; fo < 4; ++fo)
        xs[(fb * 16 + rg * 4 + r) * 520 + (fo * 16 + rb) * 8 + w] =
            f2bf(acc[fb][fo][r]);
  __syncthreads();
#pragma unroll
  for (int i = 0; i < 4; ++i) {        // 2048 (b,o) groups, 4 per thread
    const int g = i * 512 + tid;
    const int bp = g >> 6, o = g & 63;
    u16x8 v = *reinterpret_cast<const u16x8*>(xs + bp * 520 + o * 8);
    float4 lo = make_float4(bf2f(v[0]), bf2f(v[1]), bf2f(v[2]), bf2f(v[3]));
    float4 hi = make_float4(bf2f(v[4]), bf2f(v[5]), bf2f(v[6]), bf2f(v[7]));
    float* dst = out + ((size_t)(bg + bp) * NO + og + o) * NC + c0;
    *reinterpret_cast<float4*>(dst) = lo;       // 32B contiguous, 32B-aligned
    *reinterpret_cast<float4*>(dst + 4) = hi;   // (row*480 + ct*32)
  }
}

// ---- fallback (small ws): direct strided gather from x, validated in R5 ----
__global__ __launch_bounds__(512, 4) void e3mix2f(const float* __restrict__ x,
                                                  const ushort* __restrict__ wb,
                                                  const float* __restrict__ bias0,
                                                  float* __restrict__ out) {
  __shared__ ushort xs[8 * 16 * 64];
  const int bid = blockIdx.x;          // 960 = 15 ct * 64 bt
  const int ct = bid % 15, bt = bid / 15;
  const int c0 = ct * 8, bg = bt * 16;
  const int t = threadIdx.x, lane = t & 63, wid = t >> 6;
  const int sb = lane >> 2, sp = lane & 3;
  const int rb = lane & 15, rg = lane >> 4;
  const int oc = wid * 16 + rb;
  const int srow = (wid * 16 + sb) * 64;
  const int sk0 = (sp * 16) ^ ((sb & 7) << 3);
  const int sk1 = (sp * 16 + 8) ^ ((sb & 7) << 3);

  f32x4 acc[8][2];
#pragma unroll
  for (int i = 0; i < 8; ++i) { acc[i][0] = (f32x4)0.0f; acc[i][1] = (f32x4)0.0f; }
  bf16x8 w00 = {}, w01 = {}, w10 = {}, w11 = {};

#pragma unroll 1
  for (int s = 0; s < 4; ++s) {
    if (s) __syncthreads();
    u16x8 v0, v1;
    const float* src = x + (size_t)(bg + sb) * (NI * NC)
                         + (size_t)(s * 64 + sp * 16) * NC + (c0 + wid);
#pragma unroll
    for (int jj = 0; jj < 8; ++jj) v0[jj] = f2bf(src[jj * NC]);
#pragma unroll
    for (int jj = 0; jj < 8; ++jj) v1[jj] = f2bf(src[(8 + jj) * NC]);
    *reinterpret_cast<u16x8*>(&xs[srow + sk0]) = v0;
    *reinterpret_cast<u16x8*>(&xs[srow + sk1]) = v1;
    __syncthreads();

    int mprev = -1;
#pragma unroll
    for (int cc = 0; cc < 8; ++cc) {
      const int c = c0 + cc;
      const int m = c < 32 ? c : (c < 80 ? 32 + (c - 32) / 3 : 48 + (c - 80) / 5);
      if (m != mprev) {
        const ushort* wp = wb + ((size_t)((m * 32 + s * 8 + rg) * NO + oc)) * 8;
        w00 = *reinterpret_cast<const bf16x8*>(wp);
        w10 = *reinterpret_cast<const bf16x8*>(wp + (size_t)4 * NO * 8);
        w01 = *reinterpret_cast<const bf16x8*>(wp + 128 * 8);
        w11 = *reinterpret_cast<const bf16x8*>(wp + (size_t)4 * NO * 8 + 128 * 8);
        mprev = m;
      }
      const ushort* xp = xs + (cc * 16 + rb) * 64;
      const int sz = (rb & 7) << 3;
      bf16x8 a0 = *reinterpret_cast<const bf16x8*>(xp + ((rg * 8) ^ sz));
      bf16x8 a1 = *reinterpret_cast<const bf16x8*>(xp + ((32 + rg * 8) ^ sz));
      acc[cc][0] = __builtin_amdgcn_mfma_f32_16x16x32_bf16(a0, w00, acc[cc][0], 0, 0, 0);
      acc[cc][0] = __builtin_amdgcn_mfma_f32_16x16x32_bf16(a1, w10, acc[cc][0], 0, 0, 0);
      acc[cc][1] = __builtin_amdgcn_mfma_f32_16x16x32_bf16(a0, w01, acc[cc][1], 0, 0, 0);
      acc[cc][1] = __builtin_amdgcn_mfma_f32_16x16x32_bf16(a1, w11, acc[cc][1], 0, 0, 0);
    }
  }

  if (c0 < 32) {
#pragma unroll
    for (int cc = 0; cc < 8; ++cc) {
      acc[cc][0] += bias0[(c0 + cc) * NO + oc];
      acc[cc][1] += bias0[(c0 + cc) * NO + oc + 128];
    }
  }

  const int br0 = bg + rg * 4;
#pragma unroll
  for (int of = 0; of < 2; ++of)
#pragma unroll
    for (int r = 0; r < 4; ++r) {
      float4 va = make_float4(acc[0][of][r], acc[1][of][r], acc[2][of][r], acc[3][of][r]);
      float4 vb = make_float4(acc[4][of][r], acc[5][of][r], acc[6][of][r], acc[7][of][r]);
      float* dst = out + ((size_t)(br0 + r) * NO + oc + of * 128) * NC + c0;
      *reinterpret_cast<float4*>(dst) = va;
      *reinterpret_cast<float4*>(dst + 4) = vb;
    }
}

extern "C" void kernel_launch(void* const* d_in, const int* in_sizes, int n_in,
                              void* d_out, int out_size, void* d_ws, size_t ws_size,
                              hipStream_t stream) {
  const float* x  = (const float*)d_in[0];
  const float* w0 = (const float*)d_in[1];
  const float* w1 = (const float*)d_in[2];
  const float* w2 = (const float*)d_in[3];
  const float* b0 = (const float*)d_in[4];
  float* out = (float*)d_out;
  ushort* wb = (ushort*)d_ws;                       // 7.34 MB
  ushort* xt = wb + WELEMS;                         // +62.9 MB

  prep_w<<<56 * 32, 256, 0, stream>>>(w0, w1, w2, wb);
  const bool big = ws_size >= (size_t)2 * (WELEMS + XT_ELEMS);
  if (big) {
    xpose<<<4096, 256, 0, stream>>>(x, xt);
    e3mix9<<<1920, 512, 0, stream>>>(xt, wb, b0, out);
  } else {
    e3mix2f<<<960, 512, 0, stream>>>(x, wb, b0, out);
  }
}

// Round 14
// 157.901 us; speedup vs baseline: 1.1401x; 1.0251x over previous
//
#include <hip/hip_runtime.h>

typedef __attribute__((ext_vector_type(8))) short bf16x8;
typedef __attribute__((ext_vector_type(4))) float f32x4;
typedef __attribute__((ext_vector_type(8))) unsigned short u16x8;

#define DEVINL __device__ __forceinline__
#define AS1 __attribute__((address_space(1)))
#define AS3 __attribute__((address_space(3)))

constexpr int NI = 256;   // input channels (K)
constexpr int NO = 256;   // output channels
constexpr int NC = 120;   // irrep feature width
constexpr int BROW = NC * NI;                        // 30720 f32 per b of x
constexpr int CPLANE = 1024 * NI;                    // 262144: one c-plane of xt
constexpr int WELEMS = 56 * NO * NI;                 // 3,670,016
constexpr size_t XT_ELEMS = (size_t)NC * 1024 * NI;  // 31,457,280

DEVINL ushort f2bf(float x) {   // round-to-nearest-even fp32 -> bf16 bits
  unsigned u = __float_as_uint(x);
  u += 0x7FFFu + ((u >> 16) & 1u);
  return (ushort)(u >> 16);
}
DEVINL float bf2f(ushort v) { return __uint_as_float((unsigned)v << 16); }

// ---- prep: wb[((m*32 + k/8)*256 + o)*8 + k%8] = bf16(W_m[o][k]) ----
__global__ __launch_bounds__(256) void prep_w(const float* __restrict__ w0,
                                              const float* __restrict__ w1,
                                              const float* __restrict__ w2,
                                              ushort* __restrict__ wb) {
  const int m = blockIdx.x >> 5;        // 0..55
  const int kc = blockIdx.x & 31;       // k-chunk of 8
  const int o = threadIdx.x;            // 0..255
  const float* src;
  if (m < 32)      src = w0 + ((size_t)(m * NO + o)) * NI;
  else if (m < 48) src = w1 + ((size_t)((m - 32) * NO + o)) * NI;
  else             src = w2 + ((size_t)((m - 48) * NO + o)) * NI;
  src += kc * 8;
  float4 a = *reinterpret_cast<const float4*>(src);
  float4 b = *reinterpret_cast<const float4*>(src + 4);
  u16x8 p = { f2bf(a.x), f2bf(a.y), f2bf(a.z), f2bf(a.w),
              f2bf(b.x), f2bf(b.y), f2bf(b.z), f2bf(b.w) };
  *reinterpret_cast<u16x8*>(wb + ((size_t)(blockIdx.x * 256 + o)) * 8) = p;
}

// ---- pass 1 v4: x [1024 b][256 i][120 c] f32 -> xt [120 c][1024 b][256 i] bf16
// Block (b, iq): 64 i x 120 c. LDS f32 [i][c] stride 121 (write: banks 25i+c,
// free; read: 2-way, free). Output: 128B contiguous runs per (c, 8i).
__global__ __launch_bounds__(256) void xpose(const float* __restrict__ x,
                                             ushort* __restrict__ xt) {
  __shared__ float tl[64 * 121];       // 31 KB -> 5 blocks/CU
  const int bid = blockIdx.x;          // 4096 = b*4 + iq
  const int b = bid >> 2, iq = bid & 3;
  const int t = threadIdx.x;
  const float* xb = x + (size_t)b * BROW + (size_t)iq * 64 * NC;
#pragma unroll
  for (int j = 0; j < 15; ++j) {       // 7680 f32, float2 coalesced reads
    const int e = (j * 256 + t) * 2;   // even -> c even, no row wrap (c<=118)
    float2 v = *reinterpret_cast<const float2*>(xb + e);
    const int i = e / 120, c = e % 120;
    tl[i * 121 + c] = v.x;
    tl[i * 121 + c + 1] = v.y;
  }
  __syncthreads();
  ushort* dst = xt + (size_t)b * NI + iq * 64;
#pragma unroll
  for (int q = 0; q < 4; ++q) {        // 960 chunks (120 c x 8 ich), predicated
    const int chunk = q * 256 + t;
    if (chunk < 960) {
      const int c = chunk >> 3, ich = chunk & 7;
      u16x8 p;
#pragma unroll
      for (int k = 0; k < 8; ++k) p[k] = f2bf(tl[(ich * 8 + k) * 121 + c]);
      *reinterpret_cast<u16x8*>(dst + (size_t)c * CPLANE + ich * 8) = p;
    }
  }
}

// ---- pass 2 (FUSED): block = 8c x 32b x 64o, 8 waves, wave w owns c = c0+w
// (one weight matrix per wave -> 0.5 load:MFMA, W L2-resident). c-major xt:
// per-wave stage region is dense 16 KB. K=256 in 8 stages of 32 via
// global_load_lds dbuf (2x16 KB). Epilogue: R13-verified LDS repack ->
// 32B-contiguous f32 stores. Grid: ct SLOWEST (per-phase W = 1 MB per XCD).
__global__ __launch_bounds__(512, 4) void e3mixA(const ushort* __restrict__ xt,
                                                 const ushort* __restrict__ wb,
                                                 const float* __restrict__ bias0,
                                                 float* __restrict__ out) {
  __shared__ ushort xs[16640];         // union: staging 2x8192, epilogue 16632
  const int bid = blockIdx.x;          // 1920 = ct*128 + bt*4 + oq
  const int ct = bid >> 7;             // 0..14, SLOWEST
  const int bt = (bid & 127) >> 2;     // 0..31
  const int oq = bid & 3;              // fastest: 4 oq's share xt slice (L2)
  const int c0 = ct * 8, bg = bt * 32, og = oq * 64;

  const int tid = threadIdx.x, lane = tid & 63, w = tid >> 6;   // 8 waves
  const int rb = lane & 15, rg = lane >> 4;
  const int c = c0 + w;                // wave's column
  const int m = c < 32 ? c : (c < 80 ? 32 + (c - 32) / 3 : 48 + (c - 80) / 5);

  // staging: wave fills [32 b][32 k] plane; instr j covers b = 16j + (lane>>2),
  // chunk' = (lane&3) ^ ((lane>>2)&3) (involution; LDS dst linear per HW rule)
  const ushort* gsrc = xt + (size_t)c * CPLANE + (size_t)(bg + (lane >> 2)) * NI
                          + (((lane & 3) ^ ((lane >> 2) & 3)) * 8);

  f32x4 acc[2][4];                     // [fb][fo]: 32b x 64o per wave
#pragma unroll
  for (int i = 0; i < 2; ++i)
#pragma unroll
    for (int j = 0; j < 4; ++j) acc[i][j] = (f32x4)0.0f;

#define STAGEA(BUF, S)                                                         \
  do {                                                                         \
    __builtin_amdgcn_global_load_lds((const AS1 void*)(gsrc + (S) * 32),       \
        (AS3 void*)(xs + (BUF) * 8192 + w * 1024), 16, 0, 0);                  \
    __builtin_amdgcn_global_load_lds((const AS1 void*)(gsrc + (S) * 32 + 16 * NI), \
        (AS3 void*)(xs + (BUF) * 8192 + w * 1024 + 512), 16, 0, 0);            \
  } while (0)

  STAGEA(0, 0);
  __syncthreads();                     // stage 0 ready

#pragma unroll 1
  for (int s = 0; s < 8; ++s) {
    if (s < 7) STAGEA((s + 1) & 1, s + 1);      // prefetch next stage
    const ushort* xb = xs + (s & 1) * 8192 + w * 1024;    // wave's plane
    bf16x8 a[2], wf[4];
#pragma unroll
    for (int fb = 0; fb < 2; ++fb)     // A frags (4-way worst-case, 2 reads)
      a[fb] = *reinterpret_cast<const bf16x8*>(
          xb + fb * 512 + rb * 32 + ((rg ^ (rb & 3)) * 8));
#pragma unroll
    for (int fo = 0; fo < 4; ++fo)     // W frags: 4 x 256B coalesced, L2-hot
      wf[fo] = *reinterpret_cast<const bf16x8*>(
          wb + ((size_t)((m * 32 + s * 4 + rg) * NO + og + fo * 16 + rb)) * 8);
#pragma unroll
    for (int fb = 0; fb < 2; ++fb)
#pragma unroll
      for (int fo = 0; fo < 4; ++fo)
        acc[fb][fo] = __builtin_amdgcn_mfma_f32_16x16x32_bf16(a[fb], wf[fo],
                                                              acc[fb][fo], 0, 0, 0);
    __syncthreads();                   // drains prefetch; protects buf reuse
  }
#undef STAGEA

  if (c0 < 32) {                       // l=0 irreps (block-uniform): bias
#pragma unroll
    for (int fo = 0; fo < 4; ++fo) {
      const float bv = bias0[c * NO + og + fo * 16 + rb];
#pragma unroll
      for (int fb = 0; fb < 2; ++fb) acc[fb][fo] += bv;
    }
  }

  // epilogue repack (R13-verified): tile [32 b'][64 o][8 c] bf16, row stride 520
#pragma unroll
  for (int fb = 0; fb < 2; ++fb)
#pragma unroll
    for (int r = 0; r < 4; ++r)
#pragma unroll
      for (int fo = 0; fo < 4; ++fo)
        xs[(fb * 16 + rg * 4 + r) * 520 + (fo * 16 + rb) * 8 + w] =
            f2bf(acc[fb][fo][r]);
  __syncthreads();
#pragma unroll
  for (int i = 0; i < 4; ++i) {        // 2048 (b,o) groups, 4 per thread
    const int g = i * 512 + tid;
    const int bp = g >> 6, o = g & 63;
    u16x8 v = *reinterpret_cast<const u16x8*>(xs + bp * 520 + o * 8);
    float4 lo = make_float4(bf2f(v[0]), bf2f(v[1]), bf2f(v[2]), bf2f(v[3]));
    float4 hi = make_float4(bf2f(v[4]), bf2f(v[5]), bf2f(v[6]), bf2f(v[7]));
    float* dst = out + ((size_t)(bg + bp) * NO + og + o) * NC + c0;
    *reinterpret_cast<float4*>(dst) = lo;       // 32B contiguous, 32B-aligned
    *reinterpret_cast<float4*>(dst + 4) = hi;
  }
}

// ---- fallback (small ws): direct strided gather from x, validated in R5 ----
__global__ __launch_bounds__(512, 4) void e3mix2f(const float* __restrict__ x,
                                                  const ushort* __restrict__ wb,
                                                  const float* __restrict__ bias0,
                                                  float* __restrict__ out) {
  __shared__ ushort xs[8 * 16 * 64];
  const int bid = blockIdx.x;          // 960 = 15 ct * 64 bt
  const int ct = bid % 15, bt = bid / 15;
  const int c0 = ct * 8, bg = bt * 16;
  const int t = threadIdx.x, lane = t & 63, wid = t >> 6;
  const int sb = lane >> 2, sp = lane & 3;
  const int rb = lane & 15, rg = lane >> 4;
  const int oc = wid * 16 + rb;
  const int srow = (wid * 16 + sb) * 64;
  const int sk0 = (sp * 16) ^ ((sb & 7) << 3);
  const int sk1 = (sp * 16 + 8) ^ ((sb & 7) << 3);

  f32x4 acc[8][2];
#pragma unroll
  for (int i = 0; i < 8; ++i) { acc[i][0] = (f32x4)0.0f; acc[i][1] = (f32x4)0.0f; }
  bf16x8 w00 = {}, w01 = {}, w10 = {}, w11 = {};

#pragma unroll 1
  for (int s = 0; s < 4; ++s) {
    if (s) __syncthreads();
    u16x8 v0, v1;
    const float* src = x + (size_t)(bg + sb) * (NI * NC)
                         + (size_t)(s * 64 + sp * 16) * NC + (c0 + wid);
#pragma unroll
    for (int jj = 0; jj < 8; ++jj) v0[jj] = f2bf(src[jj * NC]);
#pragma unroll
    for (int jj = 0; jj < 8; ++jj) v1[jj] = f2bf(src[(8 + jj) * NC]);
    *reinterpret_cast<u16x8*>(&xs[srow + sk0]) = v0;
    *reinterpret_cast<u16x8*>(&xs[srow + sk1]) = v1;
    __syncthreads();

    int mprev = -1;
#pragma unroll
    for (int cc = 0; cc < 8; ++cc) {
      const int c = c0 + cc;
      const int m = c < 32 ? c : (c < 80 ? 32 + (c - 32) / 3 : 48 + (c - 80) / 5);
      if (m != mprev) {
        const ushort* wp = wb + ((size_t)((m * 32 + s * 8 + rg) * NO + oc)) * 8;
        w00 = *reinterpret_cast<const bf16x8*>(wp);
        w10 = *reinterpret_cast<const bf16x8*>(wp + (size_t)4 * NO * 8);
        w01 = *reinterpret_cast<const bf16x8*>(wp + 128 * 8);
        w11 = *reinterpret_cast<const bf16x8*>(wp + (size_t)4 * NO * 8 + 128 * 8);
        mprev = m;
      }
      const ushort* xp = xs + (cc * 16 + rb) * 64;
      const int sz = (rb & 7) << 3;
      bf16x8 a0 = *reinterpret_cast<const bf16x8*>(xp + ((rg * 8) ^ sz));
      bf16x8 a1 = *reinterpret_cast<const bf16x8*>(xp + ((32 + rg * 8) ^ sz));
      acc[cc][0] = __builtin_amdgcn_mfma_f32_16x16x32_bf16(a0, w00, acc[cc][0], 0, 0, 0);
      acc[cc][0] = __builtin_amdgcn_mfma_f32_16x16x32_bf16(a1, w10, acc[cc][0], 0, 0, 0);
      acc[cc][1] = __builtin_amdgcn_mfma_f32_16x16x32_bf16(a0, w01, acc[cc][1], 0, 0, 0);
      acc[cc][1] = __builtin_amdgcn_mfma_f32_16x16x32_bf16(a1, w11, acc[cc][1], 0, 0, 0);
    }
  }

  if (c0 < 32) {
#pragma unroll
    for (int cc = 0; cc < 8; ++cc) {
      acc[cc][0] += bias0[(c0 + cc) * NO + oc];
      acc[cc][1] += bias0[(c0 + cc) * NO + oc + 128];
    }
  }

  const int br0 = bg + rg * 4;
#pragma unroll
  for (int of = 0; of < 2; ++of)
#pragma unroll
    for (int r = 0; r < 4; ++r) {
      float4 va = make_float4(acc[0][of][r], acc[1][of][r], acc[2][of][r], acc[3][of][r]);
      float4 vb = make_float4(acc[4][of][r], acc[5][of][r], acc[6][of][r], acc[7][of][r]);
      float* dst = out + ((size_t)(br0 + r) * NO + oc + of * 128) * NC + c0;
      *reinterpret_cast<float4*>(dst) = va;
      *reinterpret_cast<float4*>(dst + 4) = vb;
    }
}

extern "C" void kernel_launch(void* const* d_in, const int* in_sizes, int n_in,
                              void* d_out, int out_size, void* d_ws, size_t ws_size,
                              hipStream_t stream) {
  const float* x  = (const float*)d_in[0];
  const float* w0 = (const float*)d_in[1];
  const float* w1 = (const float*)d_in[2];
  const float* w2 = (const float*)d_in[3];
  const float* b0 = (const float*)d_in[4];
  float* out = (float*)d_out;
  ushort* wb = (ushort*)d_ws;                       // 7.34 MB
  ushort* xt = wb + WELEMS;                         // +62.9 MB

  prep_w<<<56 * 32, 256, 0, stream>>>(w0, w1, w2, wb);
  const bool big = ws_size >= (size_t)2 * (WELEMS + XT_ELEMS);
  if (big) {
    xpose<<<4096, 256, 0, stream>>>(x, xt);
    e3mixA<<<1920, 512, 0, stream>>>(xt, wb, b0, out);
  } else {
    e3mix2f<<<960, 512, 0, stream>>>(x, wb, b0, out);
  }
}

// Round 15
// 141.077 us; speedup vs baseline: 1.2761x; 1.1193x over previous
//
#include <hip/hip_runtime.h>

typedef __attribute__((ext_vector_type(8))) short bf16x8;
typedef __attribute__((ext_vector_type(4))) float f32x4;
typedef __attribute__((ext_vector_type(8))) unsigned short u16x8;

#define DEVINL __device__ __forceinline__
#define AS1 __attribute__((address_space(1)))
#define AS3 __attribute__((address_space(3)))

constexpr int NI = 256;   // input channels (K)
constexpr int NO = 256;   // output channels
constexpr int NC = 120;   // irrep feature width
constexpr int BROW = NC * NI;                        // 30720 f32 per b of x
constexpr int CPLANE = 1024 * NI;                    // 262144: one c-plane of xt
constexpr int WELEMS = 56 * NO * NI;                 // 3,670,016
constexpr size_t XT_ELEMS = (size_t)NC * 1024 * NI;  // 31,457,280

DEVINL ushort f2bf(float x) {   // round-to-nearest-even fp32 -> bf16 bits
  unsigned u = __float_as_uint(x);
  u += 0x7FFFu + ((u >> 16) & 1u);
  return (ushort)(u >> 16);
}
DEVINL float bf2f(ushort v) { return __uint_as_float((unsigned)v << 16); }

// ---- prep: wb[((m*32 + k/8)*256 + o)*8 + k%8] = bf16(W_m[o][k]) ----
__global__ __launch_bounds__(256) void prep_w(const float* __restrict__ w0,
                                              const float* __restrict__ w1,
                                              const float* __restrict__ w2,
                                              ushort* __restrict__ wb) {
  const int m = blockIdx.x >> 5;        // 0..55
  const int kc = blockIdx.x & 31;       // k-chunk of 8
  const int o = threadIdx.x;            // 0..255
  const float* src;
  if (m < 32)      src = w0 + ((size_t)(m * NO + o)) * NI;
  else if (m < 48) src = w1 + ((size_t)((m - 32) * NO + o)) * NI;
  else             src = w2 + ((size_t)((m - 48) * NO + o)) * NI;
  src += kc * 8;
  float4 a = *reinterpret_cast<const float4*>(src);
  float4 b = *reinterpret_cast<const float4*>(src + 4);
  u16x8 p = { f2bf(a.x), f2bf(a.y), f2bf(a.z), f2bf(a.w),
              f2bf(b.x), f2bf(b.y), f2bf(b.z), f2bf(b.w) };
  *reinterpret_cast<u16x8*>(wb + ((size_t)(blockIdx.x * 256 + o)) * 8) = p;
}

// ---- pass 1 v4 (R14-proven ~30us): x [1024 b][256 i][120 c] f32 ->
// xt [120 c][1024 b][256 i] bf16. LDS f32 [i][c] stride 121, both phases free;
// global reads 30 KB contiguous, writes 128 B runs.
__global__ __launch_bounds__(256) void xpose(const float* __restrict__ x,
                                             ushort* __restrict__ xt) {
  __shared__ float tl[64 * 121];       // 31 KB -> 5 blocks/CU
  const int bid = blockIdx.x;          // 4096 = b*4 + iq
  const int b = bid >> 2, iq = bid & 3;
  const int t = threadIdx.x;
  const float* xb = x + (size_t)b * BROW + (size_t)iq * 64 * NC;
#pragma unroll
  for (int j = 0; j < 15; ++j) {       // 7680 f32, float2 coalesced reads
    const int e = (j * 256 + t) * 2;   // even -> c even, no row wrap (c<=118)
    float2 v = *reinterpret_cast<const float2*>(xb + e);
    const int i = e / 120, c = e % 120;
    tl[i * 121 + c] = v.x;
    tl[i * 121 + c + 1] = v.y;
  }
  __syncthreads();
  ushort* dst = xt + (size_t)b * NI + iq * 64;
#pragma unroll
  for (int q = 0; q < 4; ++q) {        // 960 chunks (120 c x 8 ich), predicated
    const int chunk = q * 256 + t;
    if (chunk < 960) {
      const int c = chunk >> 3, ich = chunk & 7;
      u16x8 p;
#pragma unroll
      for (int k = 0; k < 8; ++k) p[k] = f2bf(tl[(ich * 8 + k) * 121 + c]);
      *reinterpret_cast<u16x8*>(dst + (size_t)c * CPLANE + ich * 8) = p;
    }
  }
}

// ---- pass 2 (FUSED): block = 8c x 16b x 256o, 8 waves. Wave w owns c = c0+w
// (one W matrix per wave) and ALL 256 o (xt read exactly once -- no split).
// Staging: e3mix6-proven 128B-row global_load_lds chunk-XOR, K=256 in 4
// stages of 64, dbuf 2x16 KB. W: 2 bursts of 8 L2-resident loads per kh.
// Epilogue: R13-proven LDS repack (two 8-b halves) -> 32B-contiguous f32 out.
__global__ __launch_bounds__(512, 4) void e3mixB(const ushort* __restrict__ xt,
                                                 const ushort* __restrict__ wb,
                                                 const float* __restrict__ bias0,
                                                 float* __restrict__ out) {
  __shared__ ushort xs[16448];         // union: staging 2x8192 / epilogue 8x2056
  const int bid = blockIdx.x;          // 960 = ct*64 + bt
  const int ct = bid >> 6;             // SLOWEST: per-XCD W set = 1 ct (~1 MB, L2)
  const int bt = bid & 63;             // XCD = bid%8 = bt%8 -> balanced
  const int c0 = ct * 8, bg = bt * 16;

  const int tid = threadIdx.x, lane = tid & 63, w = tid >> 6;   // 8 waves
  const int rb = lane & 15, rg = lane >> 4;
  const int c = c0 + w;                // wave's column
  const int m = c < 32 ? c : (c < 80 ? 32 + (c - 32) / 3 : 48 + (c - 80) / 5);

  // staging: instr j covers b-rows j*8 + (lane>>3); 8 lanes x 16B = 128 B/row.
  // global chunk = (lane&7) ^ (lane>>3) -> LDS[row][slot] = chunk slot^(row&7)
  const int lr = lane >> 3;            // 0..7
  const ushort* gsrc = xt + (size_t)c * CPLANE + (size_t)(bg + lr) * NI
                          + ((lane & 7) ^ lr) * 8;

  f32x4 acc[16];                       // 256 o per wave (AGPR)
#pragma unroll
  for (int i = 0; i < 16; ++i) acc[i] = (f32x4)0.0f;

#define STAGEB(BUF, S)                                                         \
  do {                                                                         \
    __builtin_amdgcn_global_load_lds((const AS1 void*)(gsrc + (S) * 64),       \
        (AS3 void*)(xs + (BUF) * 8192 + w * 1024), 16, 0, 0);                  \
    __builtin_amdgcn_global_load_lds((const AS1 void*)(gsrc + (S) * 64 + 8 * NI), \
        (AS3 void*)(xs + (BUF) * 8192 + w * 1024 + 512), 16, 0, 0);            \
  } while (0)

  STAGEB(0, 0);
  __syncthreads();                     // stage 0 ready

#pragma unroll 1
  for (int s = 0; s < 4; ++s) {
    if (s < 3) STAGEB((s + 1) & 1, s + 1);      // prefetch next stage
    const ushort* xb = xs + (s & 1) * 8192 + w * 1024;    // wave's [16 b][64 k]
#pragma unroll
    for (int kh = 0; kh < 2; ++kh) {   // two k-halves of 32
      bf16x8 a = *reinterpret_cast<const bf16x8*>(
          xb + rb * 64 + (((kh * 4 + rg) ^ (rb & 7)) * 8));
      const ushort* wrow = wb + ((size_t)((m * 32 + s * 8 + kh * 4 + rg) * NO + rb)) * 8;
#pragma unroll
      for (int h = 0; h < 2; ++h) {    // 2 bursts of 8 W frags (32 VGPR each)
        bf16x8 wf[8];
#pragma unroll
        for (int j = 0; j < 8; ++j)
          wf[j] = *reinterpret_cast<const bf16x8*>(wrow + (h * 8 + j) * 128);
#pragma unroll
        for (int j = 0; j < 8; ++j)
          acc[h * 8 + j] = __builtin_amdgcn_mfma_f32_16x16x32_bf16(a, wf[j],
                                                                   acc[h * 8 + j], 0, 0, 0);
      }
    }
    __syncthreads();                   // drains prefetch; protects buf reuse
  }
#undef STAGEB

  if (c0 < 32) {                       // l=0 irreps (block-uniform): bias b0[c][o]
#pragma unroll
    for (int fo = 0; fo < 16; ++fo) {
      const float bv = bias0[c * NO + fo * 16 + rb];
      acc[fo] += bv;
    }
  }

  // epilogue: two 8-b halves; tile [8 b''][256 o][8 c] bf16, row stride 2056
  // (writes 2-way, reads contiguous b128). Stores: 32 B-contiguous f32 runs.
#pragma unroll 1
  for (int h = 0; h < 2; ++h) {
    __syncthreads();                   // previous reads done / staging drained
    if ((rg >> 1) == h) {              // waves' rows in this half: b' = rg*4+r
      const int brow = (rg & 1) * 4;
#pragma unroll
      for (int fo = 0; fo < 16; ++fo)
#pragma unroll
        for (int r = 0; r < 4; ++r)
          xs[(brow + r) * 2056 + (fo * 16 + rb) * 8 + w] = f2bf(acc[fo][r]);
    }
    __syncthreads();
#pragma unroll
    for (int i = 0; i < 4; ++i) {      // 2048 (b,o) groups per half, 4/thread
      const int g = i * 512 + tid;
      const int bp = g >> 8, o = g & 255;
      u16x8 v = *reinterpret_cast<const u16x8*>(xs + bp * 2056 + o * 8);
      float4 lo = make_float4(bf2f(v[0]), bf2f(v[1]), bf2f(v[2]), bf2f(v[3]));
      float4 hi = make_float4(bf2f(v[4]), bf2f(v[5]), bf2f(v[6]), bf2f(v[7]));
      float* dst = out + ((size_t)(bg + h * 8 + bp) * NO + o) * NC + c0;
      *reinterpret_cast<float4*>(dst) = lo;     // 32B contiguous, 32B-aligned
      *reinterpret_cast<float4*>(dst + 4) = hi;
    }
  }
}

// ---- fallback (small ws): direct strided gather from x, validated in R5 ----
__global__ __launch_bounds__(512, 4) void e3mix2f(const float* __restrict__ x,
                                                  const ushort* __restrict__ wb,
                                                  const float* __restrict__ bias0,
                                                  float* __restrict__ out) {
  __shared__ ushort xs[8 * 16 * 64];
  const int bid = blockIdx.x;          // 960 = 15 ct * 64 bt
  const int ct = bid % 15, bt = bid / 15;
  const int c0 = ct * 8, bg = bt * 16;
  const int t = threadIdx.x, lane = t & 63, wid = t >> 6;
  const int sb = lane >> 2, sp = lane & 3;
  const int rb = lane & 15, rg = lane >> 4;
  const int oc = wid * 16 + rb;
  const int srow = (wid * 16 + sb) * 64;
  const int sk0 = (sp * 16) ^ ((sb & 7) << 3);
  const int sk1 = (sp * 16 + 8) ^ ((sb & 7) << 3);

  f32x4 acc[8][2];
#pragma unroll
  for (int i = 0; i < 8; ++i) { acc[i][0] = (f32x4)0.0f; acc[i][1] = (f32x4)0.0f; }
  bf16x8 w00 = {}, w01 = {}, w10 = {}, w11 = {};

#pragma unroll 1
  for (int s = 0; s < 4; ++s) {
    if (s) __syncthreads();
    u16x8 v0, v1;
    const float* src = x + (size_t)(bg + sb) * (NI * NC)
                         + (size_t)(s * 64 + sp * 16) * NC + (c0 + wid);
#pragma unroll
    for (int jj = 0; jj < 8; ++jj) v0[jj] = f2bf(src[jj * NC]);
#pragma unroll
    for (int jj = 0; jj < 8; ++jj) v1[jj] = f2bf(src[(8 + jj) * NC]);
    *reinterpret_cast<u16x8*>(&xs[srow + sk0]) = v0;
    *reinterpret_cast<u16x8*>(&xs[srow + sk1]) = v1;
    __syncthreads();

    int mprev = -1;
#pragma unroll
    for (int cc = 0; cc < 8; ++cc) {
      const int c = c0 + cc;
      const int m = c < 32 ? c : (c < 80 ? 32 + (c - 32) / 3 : 48 + (c - 80) / 5);
      if (m != mprev) {
        const ushort* wp = wb + ((size_t)((m * 32 + s * 8 + rg) * NO + oc)) * 8;
        w00 = *reinterpret_cast<const bf16x8*>(wp);
        w10 = *reinterpret_cast<const bf16x8*>(wp + (size_t)4 * NO * 8);
        w01 = *reinterpret_cast<const bf16x8*>(wp + 128 * 8);
        w11 = *reinterpret_cast<const bf16x8*>(wp + (size_t)4 * NO * 8 + 128 * 8);
        mprev = m;
      }
      const ushort* xp = xs + (cc * 16 + rb) * 64;
      const int sz = (rb & 7) << 3;
      bf16x8 a0 = *reinterpret_cast<const bf16x8*>(xp + ((rg * 8) ^ sz));
      bf16x8 a1 = *reinterpret_cast<const bf16x8*>(xp + ((32 + rg * 8) ^ sz));
      acc[cc][0] = __builtin_amdgcn_mfma_f32_16x16x32_bf16(a0, w00, acc[cc][0], 0, 0, 0);
      acc[cc][0] = __builtin_amdgcn_mfma_f32_16x16x32_bf16(a1, w10, acc[cc][0], 0, 0, 0);
      acc[cc][1] = __builtin_amdgcn_mfma_f32_16x16x32_bf16(a0, w01, acc[cc][1], 0, 0, 0);
      acc[cc][1] = __builtin_amdgcn_mfma_f32_16x16x32_bf16(a1, w11, acc[cc][1], 0, 0, 0);
    }
  }

  if (c0 < 32) {
#pragma unroll
    for (int cc = 0; cc < 8; ++cc) {
      acc[cc][0] += bias0[(c0 + cc) * NO + oc];
      acc[cc][1] += bias0[(c0 + cc) * NO + oc + 128];
    }
  }

  const int br0 = bg + rg * 4;
#pragma unroll
  for (int of = 0; of < 2; ++of)
#pragma unroll
    for (int r = 0; r < 4; ++r) {
      float4 va = make_float4(acc[0][of][r], acc[1][of][r], acc[2][of][r], acc[3][of][r]);
      float4 vb = make_float4(acc[4][of][r], acc[5][of][r], acc[6][of][r], acc[7][of][r]);
      float* dst = out + ((size_t)(br0 + r) * NO + oc + of * 128) * NC + c0;
      *reinterpret_cast<float4*>(dst) = va;
      *reinterpret_cast<float4*>(dst + 4) = vb;
    }
}

extern "C" void kernel_launch(void* const* d_in, const int* in_sizes, int n_in,
                              void* d_out, int out_size, void* d_ws, size_t ws_size,
                              hipStream_t stream) {
  const float* x  = (const float*)d_in[0];
  const float* w0 = (const float*)d_in[1];
  const float* w1 = (const float*)d_in[2];
  const float* w2 = (const float*)d_in[3];
  const float* b0 = (const float*)d_in[4];
  float* out = (float*)d_out;
  ushort* wb = (ushort*)d_ws;                       // 7.34 MB
  ushort* xt = wb + WELEMS;                         // +62.9 MB

  prep_w<<<56 * 32, 256, 0, stream>>>(w0, w1, w2, wb);
  const bool big = ws_size >= (size_t)2 * (WELEMS + XT_ELEMS);
  if (big) {
    xpose<<<4096, 256, 0, stream>>>(x, xt);
    e3mixB<<<960, 512, 0, stream>>>(xt, wb, b0, out);
  } else {
    e3mix2f<<<960, 512, 0, stream>>>(x, wb, b0, out);
  }
}

// Round 16
// 134.149 us; speedup vs baseline: 1.3420x; 1.0516x over previous
//
#include <hip/hip_runtime.h>

typedef __attribute__((ext_vector_type(8))) short bf16x8;
typedef __attribute__((ext_vector_type(4))) float f32x4;
typedef __attribute__((ext_vector_type(8))) unsigned short u16x8;

#define DEVINL __device__ __forceinline__
#define AS1 __attribute__((address_space(1)))
#define AS3 __attribute__((address_space(3)))

constexpr int NI = 256;   // input channels (K)
constexpr int NO = 256;   // output channels
constexpr int NC = 120;   // irrep feature width
constexpr int BROW = NC * NI;                        // 30720 f32 per b of x
constexpr int CPLANE = 1024 * NI;                    // 262144: one c-plane of xt
constexpr int WELEMS = 56 * NO * NI;                 // 3,670,016
constexpr size_t XT_ELEMS = (size_t)NC * 1024 * NI;  // 31,457,280

DEVINL ushort f2bf(float x) {   // round-to-nearest-even fp32 -> bf16 bits
  unsigned u = __float_as_uint(x);
  u += 0x7FFFu + ((u >> 16) & 1u);
  return (ushort)(u >> 16);
}
DEVINL float bf2f(ushort v) { return __uint_as_float((unsigned)v << 16); }

// ---- prep: wb[((m*32 + k/8)*256 + o)*8 + k%8] = bf16(W_m[o][k]) ----
__global__ __launch_bounds__(256) void prep_w(const float* __restrict__ w0,
                                              const float* __restrict__ w1,
                                              const float* __restrict__ w2,
                                              ushort* __restrict__ wb) {
  const int m = blockIdx.x >> 5;        // 0..55
  const int kc = blockIdx.x & 31;       // k-chunk of 8
  const int o = threadIdx.x;            // 0..255
  const float* src;
  if (m < 32)      src = w0 + ((size_t)(m * NO + o)) * NI;
  else if (m < 48) src = w1 + ((size_t)((m - 32) * NO + o)) * NI;
  else             src = w2 + ((size_t)((m - 48) * NO + o)) * NI;
  src += kc * 8;
  float4 a = *reinterpret_cast<const float4*>(src);
  float4 b = *reinterpret_cast<const float4*>(src + 4);
  u16x8 p = { f2bf(a.x), f2bf(a.y), f2bf(a.z), f2bf(a.w),
              f2bf(b.x), f2bf(b.y), f2bf(b.z), f2bf(b.w) };
  *reinterpret_cast<u16x8*>(wb + ((size_t)(blockIdx.x * 256 + o)) * 8) = p;
}

// ---- pass 1 (R14-proven ~30us): x [1024 b][256 i][120 c] f32 ->
// xt [120 c][1024 b][256 i] bf16. LDS f32 [i][c] stride 121, both phases free;
// global reads 30 KB contiguous, writes 128 B runs.
__global__ __launch_bounds__(256) void xpose(const float* __restrict__ x,
                                             ushort* __restrict__ xt) {
  __shared__ float tl[64 * 121];       // 31 KB -> 5 blocks/CU
  const int bid = blockIdx.x;          // 4096 = b*4 + iq
  const int b = bid >> 2, iq = bid & 3;
  const int t = threadIdx.x;
  const float* xb = x + (size_t)b * BROW + (size_t)iq * 64 * NC;
#pragma unroll
  for (int j = 0; j < 15; ++j) {       // 7680 f32, float2 coalesced reads
    const int e = (j * 256 + t) * 2;   // even -> c even, no row wrap (c<=118)
    float2 v = *reinterpret_cast<const float2*>(xb + e);
    const int i = e / 120, c = e % 120;
    tl[i * 121 + c] = v.x;
    tl[i * 121 + c + 1] = v.y;
  }
  __syncthreads();
  ushort* dst = xt + (size_t)b * NI + iq * 64;
#pragma unroll
  for (int q = 0; q < 4; ++q) {        // 960 chunks (120 c x 8 ich), predicated
    const int chunk = q * 256 + t;
    if (chunk < 960) {
      const int c = chunk >> 3, ich = chunk & 7;
      u16x8 p;
#pragma unroll
      for (int k = 0; k < 8; ++k) p[k] = f2bf(tl[(ich * 8 + k) * 121 + c]);
      *reinterpret_cast<u16x8*>(dst + (size_t)c * CPLANE + ich * 8) = p;
    }
  }
}

// ---- pass 2 (R9-proven ~27us): single-matrix-per-block GEMM.
// block (c, bt): [64 b] x [256 o] x [1 c]; K=256, 4 stages via global_load_lds.
// W per block = 128 KB read once (245 MB total, L2-banded via c%8 XCD pin).
// Epilogue: bf16 IN-PLACE into xt[c][b][o] (exact region read; drained).
__global__ __launch_bounds__(256, 4) void e3mix6(ushort* xt,
                                                 const ushort* __restrict__ wb,
                                                 const float* __restrict__ bias0) {
  __shared__ ushort xs[2][64 * 64];    // 2 x 8 KB; row = 64 k (128 B), chunk-swizzled
  const int bid = blockIdx.x;          // 1920 = 16 bt x 120 c, c FASTEST
  const int c  = bid % 120;            //  (bid%8 == c%8 -> W_m pinned per XCD)
  const int bt = bid / 120;
  const int m  = c < 32 ? c : (c < 80 ? 32 + (c - 32) / 3 : 48 + (c - 80) / 5);
  const int bg = bt * 64;

  const int tid = threadIdx.x, lane = tid & 63, wid = tid >> 6;
  const int rb = lane & 15, rg = lane >> 4;
  const int wo = wid * 64;             // wave's o window (4 waves x 64 o)

  // staging: lane l, instr j in {0,1} -> row = wid*16 + j*8 + (l>>3),
  // global chunk = (l&7) ^ (row&7); LDS dst linear (HW rule).
  const int srow = wid * 16 + (lane >> 3);
  const ushort* gsrc = xt + (size_t)c * CPLANE + (size_t)(bg + srow) * NI
                          + ((lane & 7) ^ (srow & 7)) * 8;
  ushort* ldst0 = &xs[0][wid * 1024];
  ushort* ldst1 = &xs[1][wid * 1024];

  f32x4 acc[4][4];                     // [fb][fo]
#pragma unroll
  for (int i = 0; i < 4; ++i)
#pragma unroll
    for (int j = 0; j < 4; ++j) acc[i][j] = (f32x4)0.0f;

#define STAGE(LD, S)                                                          \
  do {                                                                        \
    __builtin_amdgcn_global_load_lds((const AS1 void*)(gsrc + (S) * 64),      \
                                     (AS3 void*)(LD), 16, 0, 0);              \
    __builtin_amdgcn_global_load_lds((const AS1 void*)(gsrc + (S) * 64 + 8 * NI), \
                                     (AS3 void*)((LD) + 512), 16, 0, 0);      \
  } while (0)

  STAGE(ldst0, 0);
  __syncthreads();                     // drains vmcnt: stage 0 ready

#pragma unroll 1
  for (int s = 0; s < 4; ++s) {
    if (s < 3) STAGE((s & 1) ? ldst0 : ldst1, s + 1);   // prefetch next stage
    const ushort* xb = xs[s & 1];
#pragma unroll
    for (int kh = 0; kh < 2; ++kh) {   // two k-halves of 32
      bf16x8 a[4], w[4];
#pragma unroll
      for (int fb = 0; fb < 4; ++fb)   // A frags: LDS, swizzled chunk
        a[fb] = *reinterpret_cast<const bf16x8*>(
            &xb[(fb * 16 + rb) * 64 + (((kh * 4 + rg) ^ (rb & 7)) * 8)]);
#pragma unroll
      for (int fo = 0; fo < 4; ++fo)   // W frags: 256B-coalesced L2 streams
        w[fo] = *reinterpret_cast<const bf16x8*>(
            wb + ((size_t)((m * 32 + s * 8 + kh * 4 + rg) * NO
                           + wo + fo * 16 + rb)) * 8);
#pragma unroll
      for (int fb = 0; fb < 4; ++fb)
#pragma unroll
        for (int fo = 0; fo < 4; ++fo)
          acc[fb][fo] = __builtin_amdgcn_mfma_f32_16x16x32_bf16(a[fb], w[fo],
                                                                acc[fb][fo], 0, 0, 0);
    }
    __syncthreads();                   // drains prefetch; protects buf reuse
  }
#undef STAGE

  if (c < 32) {                        // l=0 irreps: bias b0[c][o]
#pragma unroll
    for (int fo = 0; fo < 4; ++fo) {
      const float bv = bias0[c * NO + wo + fo * 16 + rb];
#pragma unroll
      for (int fb = 0; fb < 4; ++fb) acc[fb][fo] += bv;
    }
  }

  ushort* ot = xt + (size_t)c * CPLANE;
#pragma unroll
  for (int fb = 0; fb < 4; ++fb)
#pragma unroll
    for (int r = 0; r < 4; ++r) {
      const size_t brow = (size_t)(bg + fb * 16 + rg * 4 + r) * NO;
#pragma unroll
      for (int fo = 0; fo < 4; ++fo)
        ot[brow + wo + fo * 16 + rb] = f2bf(acc[fb][fo][r]);
    }
}

// ---- pass 3 (R10-proven ~33us): xt [120 c][1024 b][256 o] bf16 ->
// out [1024 b][256 o][120 c] f32. 2 o-halves per b (grid 2048, 31.7 KB LDS).
__global__ __launch_bounds__(256) void otrans(const ushort* __restrict__ xt,
                                              float* __restrict__ out) {
  __shared__ ushort tl[120 * 132];     // row stride 132 u16 (264 B, padded)
  const int bid = blockIdx.x;          // 2048 = b*2 + oh
  const int b = bid >> 1, oh = bid & 1;
  const int t = threadIdx.x;
  const ushort* src = xt + (size_t)b * NO + oh * 128;
#pragma unroll
  for (int q = 0; q < 15; ++q) {       // 3840 ushort4 chunks; 256B contiguous reads
    const int chunk = q * 256 + t;
    const int c = chunk >> 5, i0 = (chunk & 31) * 4;
    ushort4 v = *reinterpret_cast<const ushort4*>(
        src + (size_t)c * CPLANE + i0);
    *reinterpret_cast<ushort4*>(&tl[c * 132 + i0]) = v;
  }
  __syncthreads();
  const int op = t & 127, ch = t >> 7; // thread: o = oh*128+op, c-half ch
  float* dst = out + ((size_t)b * NO + oh * 128 + op) * NC + ch * 60;
#pragma unroll
  for (int j = 0; j < 15; ++j) {       // 60 c per thread: 240B contiguous run
    float4 v;
    v.x = bf2f(tl[(ch * 60 + 4 * j + 0) * 132 + op]);
    v.y = bf2f(tl[(ch * 60 + 4 * j + 1) * 132 + op]);
    v.z = bf2f(tl[(ch * 60 + 4 * j + 2) * 132 + op]);
    v.w = bf2f(tl[(ch * 60 + 4 * j + 3) * 132 + op]);
    *reinterpret_cast<float4*>(dst + 4 * j) = v;
  }
}

// ---- fallback (small ws): direct strided gather from x, validated in R5 ----
__global__ __launch_bounds__(512, 4) void e3mix2f(const float* __restrict__ x,
                                                  const ushort* __restrict__ wb,
                                                  const float* __restrict__ bias0,
                                                  float* __restrict__ out) {
  __shared__ ushort xs[8 * 16 * 64];
  const int bid = blockIdx.x;          // 960 = 15 ct * 64 bt
  const int ct = bid % 15, bt = bid / 15;
  const int c0 = ct * 8, bg = bt * 16;
  const int t = threadIdx.x, lane = t & 63, wid = t >> 6;
  const int sb = lane >> 2, sp = lane & 3;
  const int rb = lane & 15, rg = lane >> 4;
  const int oc = wid * 16 + rb;
  const int srow = (wid * 16 + sb) * 64;
  const int sk0 = (sp * 16) ^ ((sb & 7) << 3);
  const int sk1 = (sp * 16 + 8) ^ ((sb & 7) << 3);

  f32x4 acc[8][2];
#pragma unroll
  for (int i = 0; i < 8; ++i) { acc[i][0] = (f32x4)0.0f; acc[i][1] = (f32x4)0.0f; }
  bf16x8 w00 = {}, w01 = {}, w10 = {}, w11 = {};

#pragma unroll 1
  for (int s = 0; s < 4; ++s) {
    if (s) __syncthreads();
    u16x8 v0, v1;
    const float* src = x + (size_t)(bg + sb) * (NI * NC)
                         + (size_t)(s * 64 + sp * 16) * NC + (c0 + wid);
#pragma unroll
    for (int jj = 0; jj < 8; ++jj) v0[jj] = f2bf(src[jj * NC]);
#pragma unroll
    for (int jj = 0; jj < 8; ++jj) v1[jj] = f2bf(src[(8 + jj) * NC]);
    *reinterpret_cast<u16x8*>(&xs[srow + sk0]) = v0;
    *reinterpret_cast<u16x8*>(&xs[srow + sk1]) = v1;
    __syncthreads();

    int mprev = -1;
#pragma unroll
    for (int cc = 0; cc < 8; ++cc) {
      const int c = c0 + cc;
      const int m = c < 32 ? c : (c < 80 ? 32 + (c - 32) / 3 : 48 + (c - 80) / 5);
      if (m != mprev) {
        const ushort* wp = wb + ((size_t)((m * 32 + s * 8 + rg) * NO + oc)) * 8;
        w00 = *reinterpret_cast<const bf16x8*>(wp);
        w10 = *reinterpret_cast<const bf16x8*>(wp + (size_t)4 * NO * 8);
        w01 = *reinterpret_cast<const bf16x8*>(wp + 128 * 8);
        w11 = *reinterpret_cast<const bf16x8*>(wp + (size_t)4 * NO * 8 + 128 * 8);
        mprev = m;
      }
      const ushort* xp = xs + (cc * 16 + rb) * 64;
      const int sz = (rb & 7) << 3;
      bf16x8 a0 = *reinterpret_cast<const bf16x8*>(xp + ((rg * 8) ^ sz));
      bf16x8 a1 = *reinterpret_cast<const bf16x8*>(xp + ((32 + rg * 8) ^ sz));
      acc[cc][0] = __builtin_amdgcn_mfma_f32_16x16x32_bf16(a0, w00, acc[cc][0], 0, 0, 0);
      acc[cc][0] = __builtin_amdgcn_mfma_f32_16x16x32_bf16(a1, w10, acc[cc][0], 0, 0, 0);
      acc[cc][1] = __builtin_amdgcn_mfma_f32_16x16x32_bf16(a0, w01, acc[cc][1], 0, 0, 0);
      acc[cc][1] = __builtin_amdgcn_mfma_f32_16x16x32_bf16(a1, w11, acc[cc][1], 0, 0, 0);
    }
  }

  if (c0 < 32) {
#pragma unroll
    for (int cc = 0; cc < 8; ++cc) {
      acc[cc][0] += bias0[(c0 + cc) * NO + oc];
      acc[cc][1] += bias0[(c0 + cc) * NO + oc + 128];
    }
  }

  const int br0 = bg + rg * 4;
#pragma unroll
  for (int of = 0; of < 2; ++of)
#pragma unroll
    for (int r = 0; r < 4; ++r) {
      float4 va = make_float4(acc[0][of][r], acc[1][of][r], acc[2][of][r], acc[3][of][r]);
      float4 vb = make_float4(acc[4][of][r], acc[5][of][r], acc[6][of][r], acc[7][of][r]);
      float* dst = out + ((size_t)(br0 + r) * NO + oc + of * 128) * NC + c0;
      *reinterpret_cast<float4*>(dst) = va;
      *reinterpret_cast<float4*>(dst + 4) = vb;
    }
}

extern "C" void kernel_launch(void* const* d_in, const int* in_sizes, int n_in,
                              void* d_out, int out_size, void* d_ws, size_t ws_size,
                              hipStream_t stream) {
  const float* x  = (const float*)d_in[0];
  const float* w0 = (const float*)d_in[1];
  const float* w1 = (const float*)d_in[2];
  const float* w2 = (const float*)d_in[3];
  const float* b0 = (const float*)d_in[4];
  float* out = (float*)d_out;
  ushort* wb = (ushort*)d_ws;                       // 7.34 MB
  ushort* xt = wb + WELEMS;                         // +62.9 MB (xT, then outT in-place)

  prep_w<<<56 * 32, 256, 0, stream>>>(w0, w1, w2, wb);
  const bool big = ws_size >= (size_t)2 * (WELEMS + XT_ELEMS);
  if (big) {
    xpose<<<4096, 256, 0, stream>>>(x, xt);
    e3mix6<<<16 * 120, 256, 0, stream>>>(xt, wb, b0);
    otrans<<<2048, 256, 0, stream>>>(xt, out);
  } else {
    e3mix2f<<<960, 512, 0, stream>>>(x, wb, b0, out);
  }
}